// Round 12
// baseline (76.725 us; speedup 1.0000x reference)
//
#include <hip/hip_runtime.h>

// LocalCrossCorrelation3D: I,J (2,1,96,192,192) fp32 -> (loss[2], cc[2,81,192,192])
// Window (16,9,9): depth valid (96->81), h/w zero-padded +-4.
// K1 = WAVE-INDEPENDENT: each 64-lane wave owns 56 output cols + 8 halo cols
// (redundant). Depth sliding sum in regs (prefetched); 9-tap w-box as two
// 3-tap stages via ds_bpermute on fp16-packed words. No LDS arrays, NO
// barriers. ws = half2-packed (12B/voxel).
// K2 = h sliding box, full unroll + static 8-deep ring + cc + loss.

constexpr int N = 2, D = 96, H = 192, W = 192;
constexpr int OD = 81;            // D - 16 + 1
constexpr int KD = 16;
constexpr int HWp = H * W;        // 36864
constexpr float INV_WIN = 1.0f / 1296.0f;
constexpr float EPS_NZ = 3.0590232050182579e-07f;  // e^-15
constexpr int CH = 24;            // h-chunk per block in K2 (192/24 = 8)
constexpr int ODPB = 14;          // od-range per K1 wave (6 chunks cover 81)

typedef __fp16 h2 __attribute__((ext_vector_type(2)));

__device__ __forceinline__ unsigned pkrtz(float lo, float hi) {
  h2 h = __builtin_amdgcn_cvt_pkrtz(lo, hi);   // 1 instr: pack 2 f32 -> 2 f16
  unsigned u; __builtin_memcpy(&u, &h, 4); return u;
}
__device__ __forceinline__ h2 as_h2(unsigned u) {
  h2 h; __builtin_memcpy(&h, &u, 4); return h;
}
__device__ __forceinline__ unsigned as_u(h2 h) {
  unsigned u; __builtin_memcpy(&u, &h, 4); return u;
}
__device__ __forceinline__ unsigned bperm(int bidx, unsigned v) {
  return (unsigned)__builtin_amdgcn_ds_bpermute(bidx, (int)v);
}

// ---------------------------------------------------------------------------
// K1. Wave-independent. Lane l of segment s covers column wcol = s*56 + l - 4
// (l in 4..59 are outputs; l<4 / l>=60 are redundant halo). Per od:
// update running 5-ch f32 sums (enter/leave prefetched), pack to 3 half2
// words, then S9 = stage2(stage1(x)) with
//   stage1: A[l] = x[l-1]+x[l]+x[l+1]   (bperm +-1)
//   stage2: S[l] = A[l-3]+A[l]+A[l+3]   (bperm +-3)
// Validity: outputs l in 4..59 need A[1..62]; A[m] needs x[m-1..m+1] ->
// x[0..63], all intra-wave. Wrapped bperm garbage reaches only A[0]/A[63],
// which are pulled only by lanes 3/60 -> non-output lanes. Global-boundary
// columns (wcol<0 or >=W) load 0 -> sums 0, reproducing zero-pad.
// ws layout: [n][odi][h][w] x 3 uints (half2 pairs).
__global__ __launch_bounds__(256)
void k_dw(const float* __restrict__ I, const float* __restrict__ J,
          unsigned* __restrict__ ws, int od0, int c, int odcStride) {
  const int h = blockIdx.x;
  const int n = blockIdx.z;
  const int os = od0 + blockIdx.y * ODPB;
  int oe = od0 + c; if (os + ODPB < oe) oe = os + ODPB;
  if (os >= oe) return;

  const int lane = threadIdx.x & 63;
  const int seg  = threadIdx.x >> 6;          // 0..3
  const int wcol = seg * 56 + lane - 4;       // -4 .. 219
  const bool colOK = (wcol >= 0) && (wcol < W);
  const bool stOK  = (lane >= 4) && (lane < 60) && (wcol < W);

  const size_t colBase = ((size_t)n * D * H + h) * (size_t)W + wcol;
  const float* Ip = I + colBase;
  const float* Jp = J + colBase;
  unsigned* wbase = ws + ((size_t)n * odcStride * HWp + (size_t)h * W + wcol) * 3;

  // bpermute byte indices (lane*4), wrapped; garbage lands in unused lanes
  const int im1 = ((lane - 1) & 63) << 2;
  const int ip1 = ((lane + 1) & 63) << 2;
  const int im3 = ((lane - 3) & 63) << 2;
  const int ip3 = ((lane + 3) & 63) << 2;

  // warm-up: accumulate slices [os, os+KD-2] (15 slices, independent loads)
  float sI = 0.f, sJ = 0.f, sII = 0.f, sJJ = 0.f, sIJ = 0.f;
  for (int d = os; d < os + KD - 1; ++d) {
    const float iv = colOK ? Ip[(size_t)d * HWp] : 0.f;
    const float jv = colOK ? Jp[(size_t)d * HWp] : 0.f;
    sI += iv; sJ += jv;
    sII += iv * iv; sJJ += jv * jv; sIJ += iv * jv;
  }

  // prefetch first round: entering od+15, leaving od
  float eI = colOK ? Ip[(size_t)(os + KD - 1) * HWp] : 0.f;
  float eJ = colOK ? Jp[(size_t)(os + KD - 1) * HWp] : 0.f;
  float lI = colOK ? Ip[(size_t)os * HWp] : 0.f;
  float lJ = colOK ? Jp[(size_t)os * HWp] : 0.f;

  for (int od = os; od < oe; ++od) {
    const float ceI = eI, ceJ = eJ, clI = lI, clJ = lJ;
    const int odn = od + 1;
    if (odn < oe) {   // prefetch next round (awaited next iteration)
      eI = colOK ? Ip[(size_t)(odn + KD - 1) * HWp] : 0.f;
      eJ = colOK ? Jp[(size_t)(odn + KD - 1) * HWp] : 0.f;
      lI = colOK ? Ip[(size_t)odn * HWp] : 0.f;
      lJ = colOK ? Jp[(size_t)odn * HWp] : 0.f;
    }
    sI += ceI; sJ += ceJ;
    sII += ceI * ceI; sJJ += ceJ * ceJ; sIJ += ceI * ceJ;
    const unsigned x0 = pkrtz(sI, sJ);
    const unsigned x1 = pkrtz(sII, sJJ);
    const unsigned x2 = pkrtz(sIJ, 0.f);
    sI -= clI; sJ -= clJ;
    sII -= clI * clI; sJJ -= clJ * clJ; sIJ -= clI * clJ;

    // stage 1: 3-tap via bperm(+-1)
    const unsigned a0 = as_u(as_h2(bperm(im1, x0)) + as_h2(x0) + as_h2(bperm(ip1, x0)));
    const unsigned a1 = as_u(as_h2(bperm(im1, x1)) + as_h2(x1) + as_h2(bperm(ip1, x1)));
    const unsigned a2 = as_u(as_h2(bperm(im1, x2)) + as_h2(x2) + as_h2(bperm(ip1, x2)));
    // stage 2: 3-tap of stage-1 via bperm(+-3)
    const unsigned r0 = as_u(as_h2(bperm(im3, a0)) + as_h2(a0) + as_h2(bperm(ip3, a0)));
    const unsigned r1 = as_u(as_h2(bperm(im3, a1)) + as_h2(a1) + as_h2(bperm(ip3, a1)));
    const unsigned r2 = as_u(as_h2(bperm(im3, a2)) + as_h2(a2) + as_h2(bperm(ip3, a2)));

    if (stOK) {
      unsigned* o = wbase + (size_t)(od - od0) * HWp * 3;
      o[0] = r0; o[1] = r1; o[2] = r2;
    }
  }
}

// ---------------------------------------------------------------------------
// K2: 9-wide h box via fully-unrolled stream with an 8-deep static ring
// (no subtract re-loads; full unroll -> static indices + deep load pipelining)
// + one-ahead prefetch; cc formula + loss reduction.
// Block: 192 threads = w-row, grid (od, h-chunk of 24, n).
__global__ __launch_bounds__(192)
void k_hcc(const unsigned* __restrict__ ws, float* __restrict__ cc,
           float* __restrict__ acc, int od0, int odcStride) {
  const int odi = blockIdx.x;
  const int od = od0 + odi;
  const int h0 = blockIdx.y * CH;
  const int n = blockIdx.z;
  const int w = threadIdx.x;
  const unsigned* base =
      ws + ((size_t)n * odcStride * HWp + (size_t)odi * HWp + w) * 3;
  float* ccp = cc + ((size_t)n * OD + od) * (size_t)HWp + w;

  float s0 = 0.f, s1 = 0.f, s2 = 0.f, s3 = 0.f, s4 = 0.f;
  float lsum = 0.f;
  uint3 hist[8];
  const uint3 z3 = make_uint3(0u, 0u, 0u);

  // prefetch t=0 row
  uint3 vN = z3;
  {
    const int hin = h0 - 4;
    if (hin >= 0) vN = *(const uint3*)(base + (size_t)hin * W * 3);
  }
#pragma unroll
  for (int t = 0; t < CH + 8; ++t) {
    const uint3 v = vN;
    // prefetch next row
    if (t + 1 < CH + 8) {
      const int hn = h0 - 4 + t + 1;
      vN = (hn >= 0 && hn < H) ? *(const uint3*)(base + (size_t)hn * W * 3) : z3;
    }
    {
      h2 v0 = as_h2(v.x), v1 = as_h2(v.y), v2 = as_h2(v.z);
      s0 += (float)v0[0]; s1 += (float)v0[1];
      s2 += (float)v1[0]; s3 += (float)v1[1];
      s4 += (float)v2[0];
    }
    if (t >= 8) {
      const int h = h0 + t - 8;
      const float cross = s4 - s0 * s1 * INV_WIN;
      const float vI = s2 - s0 * s0 * INV_WIN;
      const float vJ = s3 - s1 * s1 * INV_WIN;
      const float prod = vI * vJ;
      const float c = (prod > EPS_NZ) ? (cross * cross) / (prod + EPS_NZ)
                                      : 1.0f / (1.0f + EPS_NZ);
      ccp[(size_t)h * W] = c;
      lsum += c;
      const uint3 q = hist[t & 7];       // row that entered 8 steps ago
      h2 q0 = as_h2(q.x), q1 = as_h2(q.y), q2 = as_h2(q.z);
      s0 -= (float)q0[0]; s1 -= (float)q0[1];
      s2 -= (float)q1[0]; s3 -= (float)q1[1];
      s4 -= (float)q2[0];
    }
    hist[t & 7] = v;                     // static index (full unroll)
  }
  __shared__ float red[3];
#pragma unroll
  for (int off = 32; off > 0; off >>= 1) lsum += __shfl_xor(lsum, off, 64);
  if ((threadIdx.x & 63) == 0) red[threadIdx.x >> 6] = lsum;
  __syncthreads();
  if (threadIdx.x == 0) atomicAdd(acc + n, red[0] + red[1] + red[2]);
}

// ---------------------------------------------------------------------------
__global__ void k_fin(const float* __restrict__ acc, float* __restrict__ out) {
  if (threadIdx.x < N)
    out[threadIdx.x] = 1.0f - acc[threadIdx.x] * (1.0f / 2985984.0f);
}

// ---------------------------------------------------------------------------
extern "C" void kernel_launch(void* const* d_in, const int* in_sizes, int n_in,
                              void* d_out, int out_size, void* d_ws,
                              size_t ws_size, hipStream_t stream) {
  const float* I = (const float*)d_in[0];
  const float* J = (const float*)d_in[1];
  float* out = (float*)d_out;
  float* acc = (float*)d_ws;                       // 2 fp32 loss accumulators
  unsigned* planes = (unsigned*)((char*)d_ws + 256);

  hipMemsetAsync(d_ws, 0, 2 * sizeof(float), stream);

  // adaptive od-chunking: packed voxel = 12B, two n-slabs
  const size_t perOdPerN = (size_t)HWp * 12;       // 442368 B
  size_t avail = (ws_size > 256) ? (ws_size - 256) : 0;
  long long odcMax = (long long)(avail / (2 * perOdPerN));
  if (odcMax < 1) odcMax = 1;
  if (odcMax > OD) odcMax = OD;
  const int odc = (int)odcMax;                     // slab stride (od entries)

  float* ccOut = out + 2;
  for (int od0 = 0; od0 < OD; od0 += odc) {
    const int c = (odc < OD - od0) ? odc : (OD - od0);
    const int S = (c + ODPB - 1) / ODPB;
    hipLaunchKernelGGL(k_dw, dim3(H, S, N), dim3(256), 0, stream,
                       I, J, planes, od0, c, odc);
    hipLaunchKernelGGL(k_hcc, dim3(c, H / CH, N), dim3(192), 0, stream,
                       planes, ccOut, acc, od0, odc);
  }
  hipLaunchKernelGGL(k_fin, dim3(1), dim3(64), 0, stream, acc, out);
}